// Round 3
// baseline (2414.727 us; speedup 1.0000x reference)
//
#include <hip/hip_runtime.h>

#define HDIM 2048
#define NL 2
#define NSTEPS 32
#define NACT 64
#define NBLK 256
#define TPB 512

typedef unsigned int u32;
typedef unsigned short u16;
typedef float f4 __attribute__((ext_vector_type(4)));
typedef u32 u32x4 __attribute__((ext_vector_type(4)));

// ---- grid-barrier state in device globals: ZERO workspace growth ----
__device__ __attribute__((aligned(1024))) u32 g_flags[NBLK];
__device__ __attribute__((aligned(1024))) u32 g_gen[64];

// ---------------- threefry2x32 (exact JAX semantics) ----------------
__device__ __forceinline__ void tf2x32(u32 k0, u32 k1, u32 x0, u32 x1,
                                       u32& o0, u32& o1) {
  u32 ks0 = k0, ks1 = k1, ks2 = k0 ^ k1 ^ 0x1BD11BDAu;
  x0 += ks0; x1 += ks1;
#define TF_R(r) { x0 += x1; x1 = (x1 << (r)) | (x1 >> (32 - (r))); x1 ^= x0; }
  TF_R(13) TF_R(15) TF_R(26) TF_R(6)   x0 += ks1; x1 += ks2 + 1u;
  TF_R(17) TF_R(29) TF_R(16) TF_R(24)  x0 += ks2; x1 += ks0 + 2u;
  TF_R(13) TF_R(15) TF_R(26) TF_R(6)   x0 += ks0; x1 += ks1 + 3u;
  TF_R(17) TF_R(29) TF_R(16) TF_R(24)  x0 += ks1; x1 += ks2 + 4u;
  TF_R(13) TF_R(15) TF_R(26) TF_R(6)   x0 += ks2; x1 += ks0 + 5u;
#undef TF_R
  o0 = x0; o1 = x1;
}

__device__ __forceinline__ float bflo(u32 u) { return __uint_as_float(u << 16); }
__device__ __forceinline__ float bfhi(u32 u) { return __uint_as_float(u & 0xFFFF0000u); }

__device__ __forceinline__ u16 to_bf16(float f) {
  u32 u = __float_as_uint(f);
  u += 0x7FFFu + ((u >> 16) & 1u);   // round-to-nearest-even
  return (u16)(u >> 16);
}

struct Params {
  const float* start_token;  // [H]
  const float* action_emb;   // [NACT][H]
  const float* head_wT;      // [NSTEPS][H][NACT] transposed head
  const float* head_b;       // [NSTEPS][NACT]
  const u16*   wih;          // [NL][4H][H] bf16
  const u16*   whh;          // [NL][4H][H] bf16
  const float* bias;         // [NL][4H]  (b_ih + b_hh)
  float* hbuf;               // [2][NL][H] double-buffered h
  float* part;               // [NACT][NBLK] per-block head partials
  float* out;                // [NSTEPS+1]
};

// ---- fully-coherent primitives: sc0+sc1 = bypass/write-through L1 and L2.
// The Infinity Cache is memory-side (always coherent), so these are
// race-safe regardless of scope-bit interpretation. No buffer_inv anywhere.
__device__ __forceinline__ void st_coh_f32(float* p, float v) {
  asm volatile("global_store_dword %0, %1, off sc0 sc1"
               :: "v"(p), "v"(v) : "memory");
}
__device__ __forceinline__ void st_coh_u32(u32* p, u32 v) {
  asm volatile("global_store_dword %0, %1, off sc0 sc1"
               :: "v"(p), "v"(v) : "memory");
}
// polling load: load + drain fused in one asm (cannot be reordered or cached)
__device__ __forceinline__ u32 ld_coh_u32(const u32* p) {
  u32 v;
  asm volatile("global_load_dword %0, %1, off sc0 sc1\n\ts_waitcnt vmcnt(0)"
               : "=v"(v) : "v"(p) : "memory");
  return v;
}

#define VM_DRAIN() do {                                  \
    asm volatile("s_waitcnt vmcnt(0)" ::: "memory");     \
    __builtin_amdgcn_sched_barrier(0);                   \
  } while (0)

// raw block barrier: drains LDS only, leaves weight prefetch in flight
#define BSYNC() do {                                       \
    asm volatile("s_waitcnt lgkmcnt(0)" ::: "memory");     \
    __builtin_amdgcn_s_barrier();                          \
    asm volatile("" ::: "memory");                         \
  } while (0)

// input vector cached load (read-only data: start_token / action_emb)
__device__ __forceinline__ void load_vec(float* r, const float* __restrict__ v,
                                         int lane) {
#pragma unroll
  for (int j = 0; j < 4; ++j) {
    float4 a = *reinterpret_cast<const float4*>(v + j * 512 + lane * 8);
    float4 b = *reinterpret_cast<const float4*>(v + j * 512 + lane * 8 + 4);
    r[j * 8 + 0] = a.x; r[j * 8 + 1] = a.y; r[j * 8 + 2] = a.z; r[j * 8 + 3] = a.w;
    r[j * 8 + 4] = b.x; r[j * 8 + 5] = b.y; r[j * 8 + 6] = b.z; r[j * 8 + 7] = b.w;
  }
}

// coherent input vector load (cross-block produced h state)
__device__ __forceinline__ void load_vec_coh(float* r, const float* v,
                                             int lane) {
  f4 t[8];
#pragma unroll
  for (int j = 0; j < 4; ++j) {
    const float* pa = v + j * 512 + lane * 8;
    const float* pb = pa + 4;
    asm volatile("global_load_dwordx4 %0, %1, off sc0 sc1"
                 : "=v"(t[2 * j + 0]) : "v"(pa) : "memory");
    asm volatile("global_load_dwordx4 %0, %1, off sc0 sc1"
                 : "=v"(t[2 * j + 1]) : "v"(pb) : "memory");
  }
  VM_DRAIN();
#pragma unroll
  for (int q = 0; q < 8; ++q) {
    r[q * 4 + 0] = t[q].x; r[q * 4 + 1] = t[q].y;
    r[q * 4 + 2] = t[q].z; r[q * 4 + 3] = t[q].w;
  }
}

// issue all 32 weight loads (plain cached: keeps L2 warm across steps)
__device__ __forceinline__ void issue8(const u16* const rows[8], int lane,
                                       uint4 wv[8][4]) {
#pragma unroll
  for (int r = 0; r < 8; ++r)
#pragma unroll
    for (int j = 0; j < 4; ++j)
      wv[r][j] = *reinterpret_cast<const uint4*>(rows[r] + j * 512 + lane * 8);
}

// FMA-consume one row; arithmetic order bit-identical to proven kernel.
__device__ __forceinline__ float consume_row(const uint4 wvr[4],
                                             const float* xr) {
  float acc = 0.f;
#pragma unroll
  for (int j = 0; j < 4; ++j) {
    uint4 wvv = wvr[j];
    acc = fmaf(bflo(wvv.x), xr[j * 8 + 0], acc);
    acc = fmaf(bfhi(wvv.x), xr[j * 8 + 1], acc);
    acc = fmaf(bflo(wvv.y), xr[j * 8 + 2], acc);
    acc = fmaf(bfhi(wvv.y), xr[j * 8 + 3], acc);
    acc = fmaf(bflo(wvv.z), xr[j * 8 + 4], acc);
    acc = fmaf(bfhi(wvv.z), xr[j * 8 + 5], acc);
    acc = fmaf(bflo(wvv.w), xr[j * 8 + 6], acc);
    acc = fmaf(bfhi(wvv.w), xr[j * 8 + 7], acc);
  }
  return acc;
}

__device__ __forceinline__ float wave_sum(float v) {
#pragma unroll
  for (int off = 32; off > 0; off >>= 1) v += __shfl_xor(v, off);
  return v;
}

// ---- grid barrier: per-block arrival flags, block-0 wave-0 parallel scan,
// single gen publish. All traffic via explicit sc0sc1 (MALL-coherent).
__device__ __forceinline__ void gbar(u32 target, int tid, int bid) {
  asm volatile("s_waitcnt lgkmcnt(0)" ::: "memory");
  __builtin_amdgcn_s_barrier();
  if (bid == 0) {
    if (tid < 64) {  // wave 0: arrive, scan all 256 flags (4 per lane), publish
      if (tid == 0) {
        asm volatile("s_waitcnt vmcnt(0)" ::: "memory");  // release data
        st_coh_u32(&g_flags[0], target);
      }
      const u32* fp = &g_flags[tid * 4];
      for (;;) {
        u32x4 fv;
        asm volatile(
            "global_load_dwordx4 %0, %1, off sc0 sc1\n\ts_waitcnt vmcnt(0)"
            : "=v"(fv) : "v"(fp) : "memory");
        if (__all(fv.x >= target && fv.y >= target && fv.z >= target &&
                  fv.w >= target))
          break;
        __builtin_amdgcn_s_sleep(1);
      }
      if (tid == 0) st_coh_u32(&g_gen[0], target);
    }
  } else if (tid == 0) {
    asm volatile("s_waitcnt vmcnt(0)" ::: "memory");  // release data
    st_coh_u32(&g_flags[bid], target);
    while (ld_coh_u32(&g_gen[0]) < target) __builtin_amdgcn_s_sleep(1);
  }
  __builtin_amdgcn_s_barrier();
  asm volatile("" ::: "memory");
}

// waves_per_eu(2,2): EXACT 2 waves/SIMD -> 256-VGPR budget per thread.
// Grid barrier pins us to 1 block/CU (8 waves = 2/SIMD) anyway; round-2's
// min-only launch_bounds let the allocator chase 4 waves/EU and spill the
// 128-VGPR weight prefetch buffer to scratch (WRITE_SIZE 1.84 GB).
__global__ void
__attribute__((amdgpu_flat_work_group_size(TPB, TPB),
               amdgpu_waves_per_eu(2, 2)))
lstm_main(Params p) {
  const int tid = threadIdx.x;
  const int bid = blockIdx.x;
  const int lane = tid & 63;
  const int w = tid >> 6;        // wave 0..7
  const int m = w & 1;           // 0 -> w_ih side, 1 -> w_hh side
  const int pairc = w >> 1;      // 0..3 -> cells {2p, 2p+1} within block
  const int cell0 = bid * 8;

  __shared__ float part_l[8][8];    // [wave][ci*4+gate]
  __shared__ float gates[8][4];     // [cell][gate]
  __shared__ float h1loc[8];        // layer-1 h for this block's cells
  __shared__ float lds_logits[NACT];

  const u16* Wl0 = (m == 0) ? p.wih : p.whh;
  const u16* Wl1 = Wl0 + (size_t)4 * HDIM * HDIM;
  const u16* rows0[8];
  const u16* rows1[8];
#pragma unroll
  for (int ci = 0; ci < 2; ++ci)
#pragma unroll
    for (int g = 0; g < 4; ++g) {
      const size_t r = (size_t)g * HDIM + cell0 + 2 * pairc + ci;
      rows0[ci * 4 + g] = Wl0 + r * HDIM;
      rows1[ci * 4 + g] = Wl1 + r * HDIM;
    }

  float b0v = 0.f, b1v = 0.f;
  if (tid < 32) {
    const int c = tid >> 2, g = tid & 3;
    b0v = p.bias[g * HDIM + cell0 + c];
    b1v = p.bias[4 * HDIM + g * HDIM + cell0 + c];
  }

  float c0 = 0.f, c1 = 0.f;  // cell state (meaningful for tid<8)
  float logp_sum = 0.f;
  int act = 0;
  u32 bt = 0;
  float vr[32];
  uint4 wv[8][4];            // 128-VGPR persistent weight prefetch buffer

  issue8(rows0, lane, wv);   // prologue: layer-0 weights for step 0

  for (int s = 0; s < NSTEPS; ++s) {
    const int pr = s & 1, pw = (s + 1) & 1;

    // ================= layer 0 =================
    {
      if (m == 0) {
        const float* x = (s == 0) ? p.start_token
                                  : p.action_emb + (size_t)act * HDIM;
        load_vec(vr, x, lane);                       // read-only: cached
      } else {
        load_vec_coh(vr, p.hbuf + (size_t)(pr * NL + 0) * HDIM, lane);
      }
      float acc[8];
#pragma unroll
      for (int r = 0; r < 8; ++r) acc[r] = consume_row(wv[r], vr);
      issue8(rows1, lane, wv);   // prefetch layer-1 weights across the barrier
#pragma unroll
      for (int r = 0; r < 8; ++r) {
        float v = wave_sum(acc[r]);
        if (lane == 0) part_l[w][r] = v;
      }
      BSYNC();
      if (tid < 32) {
        const int c = tid >> 2, g = tid & 3;
        const int w0 = (c >> 1) * 2, idx = (c & 1) * 4 + g;
        gates[c][g] = part_l[w0][idx] + part_l[w0 + 1][idx] + b0v;
      }
      // gates: written lanes 0-31, read lanes 0-7 (same wave, in-order DS)
      if (tid < 8) {
        float gi = 1.f / (1.f + expf(-gates[tid][0]));
        float gf = 1.f / (1.f + expf(-gates[tid][1]));
        float gg = tanhf(gates[tid][2]);
        float go = 1.f / (1.f + expf(-gates[tid][3]));
        c0 = gf * c0 + gi * gg;
        float h = go * tanhf(c0);
        st_coh_f32(&p.hbuf[(size_t)(pw * NL + 0) * HDIM + cell0 + tid], h);
      }
      gbar(++bt, tid, bid);  // h0(new) visible grid-wide
    }

    // ================= layer 1 (+ head partial) =================
    {
      float hw[8];
      if (w == 0) {  // head weights early (read-only, cached)
        const float* hwp =
            p.head_wT + ((size_t)s * HDIM + cell0) * NACT + lane;
#pragma unroll
        for (int c = 0; c < 8; ++c) hw[c] = hwp[c * NACT];
      }
      if (m == 0)
        load_vec_coh(vr, p.hbuf + (size_t)(pw * NL + 0) * HDIM, lane);
      else
        load_vec_coh(vr, p.hbuf + (size_t)(pr * NL + 1) * HDIM, lane);
      float acc[8];
#pragma unroll
      for (int r = 0; r < 8; ++r) acc[r] = consume_row(wv[r], vr);
      if (s != NSTEPS - 1) issue8(rows0, lane, wv);  // prefetch next step l0
#pragma unroll
      for (int r = 0; r < 8; ++r) {
        float v = wave_sum(acc[r]);
        if (lane == 0) part_l[w][r] = v;
      }
      BSYNC();
      if (tid < 32) {
        const int c = tid >> 2, g = tid & 3;
        const int w0 = (c >> 1) * 2, idx = (c & 1) * 4 + g;
        gates[c][g] = part_l[w0][idx] + part_l[w0 + 1][idx] + b1v;
      }
      if (tid < 8) {
        float gi = 1.f / (1.f + expf(-gates[tid][0]));
        float gf = 1.f / (1.f + expf(-gates[tid][1]));
        float gg = tanhf(gates[tid][2]);
        float go = 1.f / (1.f + expf(-gates[tid][3]));
        c1 = gf * c1 + gi * gg;
        float h = go * tanhf(c1);
        st_coh_f32(&p.hbuf[(size_t)(pw * NL + 1) * HDIM + cell0 + tid], h);
        h1loc[tid] = h;
      }
      // h1loc: written lanes 0-7, read lanes 0-63 (same wave, in-order DS)
      if (w == 0) {
        float a2 = 0.f;
#pragma unroll
        for (int c = 0; c < 8; ++c) a2 = fmaf(hw[c], h1loc[c], a2);
        st_coh_f32(&p.part[(size_t)lane * NBLK + bid], a2);
      }
      gbar(++bt, tid, bid);  // all 256 partials visible grid-wide
    }

    // ================= deterministic logits reduce =================
    {
      const int a = tid >> 3, j = tid & 7;  // 8 threads per action
      const float* pb = p.part + (size_t)a * NBLK + j * 32;
      f4 t[8];
#pragma unroll
      for (int q = 0; q < 8; ++q) {
        const float* pq = pb + q * 4;
        asm volatile("global_load_dwordx4 %0, %1, off sc0 sc1"
                     : "=v"(t[q]) : "v"(pq) : "memory");
      }
      VM_DRAIN();
      float sum = 0.f;
#pragma unroll
      for (int q = 0; q < 8; ++q) sum += t[q].x + t[q].y + t[q].z + t[q].w;
      sum += __shfl_xor(sum, 1);
      sum += __shfl_xor(sum, 2);
      sum += __shfl_xor(sum, 4);
      if (j == 0) lds_logits[a] = sum;
    }
    BSYNC();

    // ====== sampling (partitionable threefry, jax>=0.4.30 default) ======
    {
      float logit = lds_logits[lane] + p.head_b[s * NACT + lane];

      u32 kA, kB;
      tf2x32(0u, 42u, 0u, (u32)s, kA, kB);
      u32 y0, y1;
      tf2x32(kA, kB, 0u, (u32)lane, y0, y1);
      u32 bits = y0 ^ y1;

      float uf = __uint_as_float(0x3f800000u | (bits >> 9)) - 1.0f;
      const float tiny = 1.17549435e-38f;
      float u = fmaxf(tiny, uf + tiny);
      float gum = -logf(-logf(u));

      float score = logit + gum;
      int bi = lane;
      float bs = score;
#pragma unroll
      for (int off = 32; off > 0; off >>= 1) {
        float os = __shfl_xor(bs, off);
        int oi = __shfl_xor(bi, off);
        if (os > bs || (os == bs && oi < bi)) { bs = os; bi = oi; }
      }
      float mx = logit;
#pragma unroll
      for (int off = 32; off > 0; off >>= 1) mx = fmaxf(mx, __shfl_xor(mx, off));
      float se = wave_sum(expf(logit - mx));
      float la = __shfl(logit, bi);
      logp_sum += la - mx - logf(se);
      act = bi;
      if (bid == 0 && tid == 0) p.out[s] = (float)bi;
    }
    // lds_logits reuse protected by next step's barriers
  }
  if (bid == 0 && tid == 0) p.out[NSTEPS] = logp_sum;
}

// -------- init: f32->bf16 weights, head transpose, combined bias, zeroing ----
__global__ void init_kernel(const float* __restrict__ wih,
                            const float* __restrict__ whh,
                            const float* __restrict__ bih,
                            const float* __restrict__ bhh,
                            const float* __restrict__ head_w,
                            u16* __restrict__ wih_bf, u16* __restrict__ whh_bf,
                            float* __restrict__ head_wT,
                            float* __restrict__ bias, float* __restrict__ hbuf) {
  const size_t idx = (size_t)blockIdx.x * blockDim.x + threadIdx.x;
  const size_t stride = (size_t)gridDim.x * blockDim.x;
  const size_t n4 = (size_t)NL * 4 * HDIM * HDIM / 4;  // float4 count
  for (size_t k = idx; k < n4; k += stride) {
    float4 a = reinterpret_cast<const float4*>(wih)[k];
    float4 b = reinterpret_cast<const float4*>(whh)[k];
    ushort4 ua, ub;
    ua.x = to_bf16(a.x); ua.y = to_bf16(a.y);
    ua.z = to_bf16(a.z); ua.w = to_bf16(a.w);
    ub.x = to_bf16(b.x); ub.y = to_bf16(b.y);
    ub.z = to_bf16(b.z); ub.w = to_bf16(b.w);
    reinterpret_cast<ushort4*>(wih_bf)[k] = ua;
    reinterpret_cast<ushort4*>(whh_bf)[k] = ub;
  }
  // head_wT[s][h][a] = head_w[s][a][h]
  for (size_t k = idx; k < (size_t)NSTEPS * HDIM * NACT; k += stride) {
    const int a = (int)(k & (NACT - 1));
    const int h = (int)((k >> 6) & (HDIM - 1));
    const int s = (int)(k >> 17);
    head_wT[k] = head_w[((size_t)s * NACT + a) * HDIM + h];
  }
  for (size_t k = idx; k < (size_t)NL * 4 * HDIM; k += stride)
    bias[k] = bih[k] + bhh[k];
  for (size_t k = idx; k < (size_t)2 * NL * HDIM; k += stride) hbuf[k] = 0.f;
  // barrier state reset each launch (kernel-boundary release makes it visible)
  for (size_t k = idx; k < NBLK; k += stride) g_flags[k] = 0u;
  for (size_t k = idx; k < 64; k += stride) g_gen[k] = 0u;
}

extern "C" void kernel_launch(void* const* d_in, const int* in_sizes, int n_in,
                              void* d_out, int out_size, void* d_ws,
                              size_t ws_size, hipStream_t stream) {
  (void)in_sizes; (void)n_in; (void)out_size; (void)ws_size;
  const float* start_token = (const float*)d_in[0];
  const float* action_emb  = (const float*)d_in[1];
  const float* w_ih        = (const float*)d_in[2];
  const float* w_hh        = (const float*)d_in[3];
  const float* b_ih        = (const float*)d_in[4];
  const float* b_hh        = (const float*)d_in[5];
  const float* head_w      = (const float*)d_in[6];
  const float* head_b      = (const float*)d_in[7];

  char* ws = (char*)d_ws;
  const size_t WN = (size_t)NL * 4 * HDIM * HDIM;      // 33,554,432 elems
  u16* wih_bf    = (u16*)ws;                           // WN*2 bytes
  u16* whh_bf    = (u16*)(ws + WN * 2);                // WN*2 bytes
  size_t off     = WN * 4;
  float* head_wT = (float*)(ws + off); off += (size_t)NSTEPS * HDIM * NACT * 4;
  float* bias    = (float*)(ws + off); off += (size_t)NL * 4 * HDIM * 4;
  float* hbuf    = (float*)(ws + off); off += (size_t)2 * NL * HDIM * 4;
  float* partb   = (float*)(ws + off); off += (size_t)NACT * NBLK * 4;
  // NOTE: identical workspace footprint to the proven kernels.

  init_kernel<<<dim3(2048), dim3(256), 0, stream>>>(
      w_ih, w_hh, b_ih, b_hh, head_w, wih_bf, whh_bf, head_wT, bias, hbuf);

  Params p;
  p.start_token = start_token;
  p.action_emb = action_emb;
  p.head_wT = head_wT;
  p.head_b = head_b;
  p.wih = wih_bf;
  p.whh = whh_bf;
  p.bias = bias;
  p.hbuf = hbuf;
  p.part = partb;
  p.out = (float*)d_out;

  lstm_main<<<dim3(NBLK), dim3(TPB), 0, stream>>>(p);
}

// Round 5
// 2003.993 us; speedup vs baseline: 1.2050x; 1.2050x over previous
//
#include <hip/hip_runtime.h>

#define HDIM 2048
#define NL 2
#define NSTEPS 32
#define NACT 64
#define NBLK 256
#define TPB 512
#define SPIN_MAX (1 << 20)   // failsafe bound: never wedge the GPU

typedef unsigned int u32;
typedef unsigned short u16;
typedef float f4 __attribute__((ext_vector_type(4)));
typedef u32 u32x4 __attribute__((ext_vector_type(4)));

// ---- grid-barrier state in device globals: ZERO workspace growth ----
__device__ __attribute__((aligned(1024))) u32 g_flags[NBLK];
__device__ __attribute__((aligned(1024))) u32 g_gen[64];

// ---------------- threefry2x32 (exact JAX semantics) ----------------
__device__ __forceinline__ void tf2x32(u32 k0, u32 k1, u32 x0, u32 x1,
                                       u32& o0, u32& o1) {
  u32 ks0 = k0, ks1 = k1, ks2 = k0 ^ k1 ^ 0x1BD11BDAu;
  x0 += ks0; x1 += ks1;
#define TF_R(r) { x0 += x1; x1 = (x1 << (r)) | (x1 >> (32 - (r))); x1 ^= x0; }
  TF_R(13) TF_R(15) TF_R(26) TF_R(6)   x0 += ks1; x1 += ks2 + 1u;
  TF_R(17) TF_R(29) TF_R(16) TF_R(24)  x0 += ks2; x1 += ks0 + 2u;
  TF_R(13) TF_R(15) TF_R(26) TF_R(6)   x0 += ks0; x1 += ks1 + 3u;
  TF_R(17) TF_R(29) TF_R(16) TF_R(24)  x0 += ks1; x1 += ks2 + 4u;
  TF_R(13) TF_R(15) TF_R(26) TF_R(6)   x0 += ks2; x1 += ks0 + 5u;
#undef TF_R
  o0 = x0; o1 = x1;
}

__device__ __forceinline__ float bflo(u32 u) { return __uint_as_float(u << 16); }
__device__ __forceinline__ float bfhi(u32 u) { return __uint_as_float(u & 0xFFFF0000u); }

__device__ __forceinline__ u16 to_bf16(float f) {
  u32 u = __float_as_uint(f);
  u += 0x7FFFu + ((u >> 16) & 1u);   // round-to-nearest-even
  return (u16)(u >> 16);
}

struct Params {
  const float* start_token;  // [H]
  const float* action_emb;   // [NACT][H]
  const float* head_wT;      // [NSTEPS][H][NACT] transposed head
  const float* head_b;       // [NSTEPS][NACT]
  const u16*   wih;          // [NL][4H][H] bf16
  const u16*   whh;          // [NL][4H][H] bf16
  const float* bias;         // [NL][4H]  (b_ih + b_hh)
  float* hbuf;               // [2][NL][H] double-buffered h
  float* part;               // [NACT][NBLK] per-block head partials
  float* out;                // [NSTEPS+1]
};

// ---- fully-coherent primitives: sc0+sc1 = bypass/write-through L1 and L2.
__device__ __forceinline__ void st_coh_f32(float* p, float v) {
  asm volatile("global_store_dword %0, %1, off sc0 sc1"
               :: "v"(p), "v"(v) : "memory");
}
__device__ __forceinline__ void st_coh_u32(u32* p, u32 v) {
  asm volatile("global_store_dword %0, %1, off sc0 sc1"
               :: "v"(p), "v"(v) : "memory");
}
// polling load: load + drain fused in one asm (cannot be reordered or cached)
__device__ __forceinline__ u32 ld_coh_u32(const u32* p) {
  u32 v;
  asm volatile("global_load_dword %0, %1, off sc0 sc1\n\ts_waitcnt vmcnt(0)"
               : "=v"(v) : "v"(p) : "memory");
  return v;
}

#define VM_DRAIN() do {                                  \
    asm volatile("s_waitcnt vmcnt(0)" ::: "memory");     \
    __builtin_amdgcn_sched_barrier(0);                   \
  } while (0)

// raw block barrier: drains LDS only, leaves weight prefetch in flight
#define BSYNC() do {                                       \
    asm volatile("s_waitcnt lgkmcnt(0)" ::: "memory");     \
    __builtin_amdgcn_s_barrier();                          \
    asm volatile("" ::: "memory");                         \
  } while (0)

// input vector cached load (read-only data: start_token / action_emb)
__device__ __forceinline__ void load_vec(float* r, const float* __restrict__ v,
                                         int lane) {
#pragma unroll
  for (int j = 0; j < 4; ++j) {
    float4 a = *reinterpret_cast<const float4*>(v + j * 512 + lane * 8);
    float4 b = *reinterpret_cast<const float4*>(v + j * 512 + lane * 8 + 4);
    r[j * 8 + 0] = a.x; r[j * 8 + 1] = a.y; r[j * 8 + 2] = a.z; r[j * 8 + 3] = a.w;
    r[j * 8 + 4] = b.x; r[j * 8 + 5] = b.y; r[j * 8 + 6] = b.z; r[j * 8 + 7] = b.w;
  }
}

// coherent input vector load (cross-block produced h state)
__device__ __forceinline__ void load_vec_coh(float* r, const float* v,
                                             int lane) {
  f4 t[8];
#pragma unroll
  for (int j = 0; j < 4; ++j) {
    const float* pa = v + j * 512 + lane * 8;
    const float* pb = pa + 4;
    asm volatile("global_load_dwordx4 %0, %1, off sc0 sc1"
                 : "=v"(t[2 * j + 0]) : "v"(pa) : "memory");
    asm volatile("global_load_dwordx4 %0, %1, off sc0 sc1"
                 : "=v"(t[2 * j + 1]) : "v"(pb) : "memory");
  }
  VM_DRAIN();
#pragma unroll
  for (int q = 0; q < 8; ++q) {
    r[q * 4 + 0] = t[q].x; r[q * 4 + 1] = t[q].y;
    r[q * 4 + 2] = t[q].z; r[q * 4 + 3] = t[q].w;
  }
}

// ---- quarter-row weight pipeline ----------------------------------------
// Issue loads for quarter j (8 rows x 1 dwordx4 = 8 KB/wave) via asm volatile:
// the compiler cannot hoist/merge them, so register demand stays at one
// 32-VGPR buffer (the round-2/3 full-phase prefetch spilled at 128 VGPRs).
// NOTE: operand type MUST be ext_vector (u32x4), not HIP's struct uint4 —
// struct types are invalid for "v" asm constraints (round-4 compile failure).
__device__ __forceinline__ void issue_q(const u16* const rows[8], int j,
                                        int lane, u32x4 q[8]) {
#pragma unroll
  for (int r = 0; r < 8; ++r) {
    const u16* ptr = rows[r] + j * 512 + lane * 8;
    asm volatile("global_load_dwordx4 %0, %1, off"
                 : "=v"(q[r]) : "v"(ptr));
  }
}

// FMA-consume quarter j; per-accumulator chain order (j=0,1,2,3, elements
// in order within each j) is bit-identical to the proven kernel.
__device__ __forceinline__ void consume_q(const u32x4 q[8], const float* xr,
                                          int j, float acc[8]) {
#pragma unroll
  for (int r = 0; r < 8; ++r) {
    u32x4 wvv = q[r];
    acc[r] = fmaf(bflo(wvv.x), xr[j * 8 + 0], acc[r]);
    acc[r] = fmaf(bfhi(wvv.x), xr[j * 8 + 1], acc[r]);
    acc[r] = fmaf(bflo(wvv.y), xr[j * 8 + 2], acc[r]);
    acc[r] = fmaf(bfhi(wvv.y), xr[j * 8 + 3], acc[r]);
    acc[r] = fmaf(bflo(wvv.z), xr[j * 8 + 4], acc[r]);
    acc[r] = fmaf(bfhi(wvv.z), xr[j * 8 + 5], acc[r]);
    acc[r] = fmaf(bflo(wvv.w), xr[j * 8 + 6], acc[r]);
    acc[r] = fmaf(bfhi(wvv.w), xr[j * 8 + 7], acc[r]);
  }
}

__device__ __forceinline__ float wave_sum(float v) {
#pragma unroll
  for (int off = 32; off > 0; off >>= 1) v += __shfl_xor(v, off);
  return v;
}

// ---- grid barrier: per-block arrival flags, block-0 wave-0 parallel scan,
// single gen publish. All traffic via explicit sc0sc1 (MALL-coherent).
// Spins are BOUNDED: on pathological failure the kernel terminates with
// wrong results instead of wedging the container.
__device__ __forceinline__ void gbar(u32 target, int tid, int bid) {
  asm volatile("s_waitcnt lgkmcnt(0)" ::: "memory");
  __builtin_amdgcn_s_barrier();
  if (bid == 0) {
    if (tid < 64) {  // wave 0: arrive, scan all 256 flags (4 per lane), publish
      if (tid == 0) {
        asm volatile("s_waitcnt vmcnt(0)" ::: "memory");  // release data
        st_coh_u32(&g_flags[0], target);
      }
      const u32* fp = &g_flags[tid * 4];
      int it = 0;
      for (;;) {
        u32x4 fv;
        asm volatile(
            "global_load_dwordx4 %0, %1, off sc0 sc1\n\ts_waitcnt vmcnt(0)"
            : "=v"(fv) : "v"(fp) : "memory");
        if (__all(fv.x >= target && fv.y >= target && fv.z >= target &&
                  fv.w >= target))
          break;
        if (++it > SPIN_MAX) break;  // failsafe
        __builtin_amdgcn_s_sleep(1);
      }
      if (tid == 0) st_coh_u32(&g_gen[0], target);
    }
  } else if (tid == 0) {
    asm volatile("s_waitcnt vmcnt(0)" ::: "memory");  // release data
    st_coh_u32(&g_flags[bid], target);
    int it = 0;
    while (ld_coh_u32(&g_gen[0]) < target) {
      if (++it > SPIN_MAX) break;  // failsafe
      __builtin_amdgcn_s_sleep(1);
    }
  }
  __builtin_amdgcn_s_barrier();
  asm volatile("" ::: "memory");
}

__global__ void __launch_bounds__(TPB, 2) lstm_main(Params p) {
  const int tid = threadIdx.x;
  const int bid = blockIdx.x;
  const int lane = tid & 63;
  // scalarize wave index -> row bases live in SGPRs, not VGPRs
  const int wu = __builtin_amdgcn_readfirstlane(tid >> 6);  // wave 0..7
  const int w = wu;
  const int m = wu & 1;          // 0 -> w_ih side, 1 -> w_hh side
  const int pairc = wu >> 1;     // 0..3 -> cells {2p, 2p+1} within block
  const int cell0 = bid * 8;

  __shared__ float part_l[8][8];    // [wave][ci*4+gate]
  __shared__ float gates[8][4];     // [cell][gate]
  __shared__ float h1loc[8];        // layer-1 h for this block's cells
  __shared__ float lds_logits[NACT];

  const u16* Wl0 = (m == 0) ? p.wih : p.whh;
  const u16* Wl1 = Wl0 + (size_t)4 * HDIM * HDIM;
  const u16* rows0[8];
  const u16* rows1[8];
#pragma unroll
  for (int ci = 0; ci < 2; ++ci)
#pragma unroll
    for (int g = 0; g < 4; ++g) {
      const size_t r = (size_t)g * HDIM + cell0 + 2 * pairc + ci;
      rows0[ci * 4 + g] = Wl0 + r * HDIM;
      rows1[ci * 4 + g] = Wl1 + r * HDIM;
    }

  float b0v = 0.f, b1v = 0.f;
  if (tid < 32) {
    const int c = tid >> 2, g = tid & 3;
    b0v = p.bias[g * HDIM + cell0 + c];
    b1v = p.bias[4 * HDIM + g * HDIM + cell0 + c];
  }

  float c0 = 0.f, c1 = 0.f;  // cell state (meaningful for tid<8)
  float logp_sum = 0.f;
  int act = 0;
  u32 bt = 0;
  float vr[32];
  u32x4 qA[8];               // single 32-VGPR quarter buffer (no spill)

  issue_q(rows0, 0, lane, qA);   // prologue: L0 quarter 0 of step 0

  for (int s = 0; s < NSTEPS; ++s) {
    const int pr = s & 1, pw = (s + 1) & 1;

    // ================= layer 0 =================
    {
      if (m == 0) {
        const float* x = (s == 0) ? p.start_token
                                  : p.action_emb + (size_t)act * HDIM;
        load_vec(vr, x, lane);                       // read-only: cached
      } else {
        load_vec_coh(vr, p.hbuf + (size_t)(pr * NL + 0) * HDIM, lane);
      }
      float acc[8];
#pragma unroll
      for (int r = 0; r < 8; ++r) acc[r] = 0.f;
#pragma unroll
      for (int j = 0; j < 4; ++j) {
        VM_DRAIN();                      // quarter j (and vr on j=0) arrived
        consume_q(qA, vr, j, acc);
        if (j < 3) issue_q(rows0, j + 1, lane, qA);
      }
      issue_q(rows1, 0, lane, qA);       // prefetch L1 quarter 0 across barrier
#pragma unroll
      for (int r = 0; r < 8; ++r) {
        float v = wave_sum(acc[r]);
        if (lane == 0) part_l[w][r] = v;
      }
      BSYNC();
      if (tid < 32) {
        const int c = tid >> 2, g = tid & 3;
        const int w0 = (c >> 1) * 2, idx = (c & 1) * 4 + g;
        gates[c][g] = part_l[w0][idx] + part_l[w0 + 1][idx] + b0v;
      }
      // gates: written lanes 0-31, read lanes 0-7 (same wave, in-order DS)
      if (tid < 8) {
        float gi = 1.f / (1.f + expf(-gates[tid][0]));
        float gf = 1.f / (1.f + expf(-gates[tid][1]));
        float gg = tanhf(gates[tid][2]);
        float go = 1.f / (1.f + expf(-gates[tid][3]));
        c0 = gf * c0 + gi * gg;
        float h = go * tanhf(c0);
        st_coh_f32(&p.hbuf[(size_t)(pw * NL + 0) * HDIM + cell0 + tid], h);
      }
      gbar(++bt, tid, bid);  // h0(new) visible grid-wide
    }

    // ================= layer 1 (+ head partial) =================
    {
      float hw[8];
      if (w == 0) {  // head weights early (read-only, cached)
        const float* hwp =
            p.head_wT + ((size_t)s * HDIM + cell0) * NACT + lane;
#pragma unroll
        for (int c = 0; c < 8; ++c) hw[c] = hwp[c * NACT];
      }
      if (m == 0)
        load_vec_coh(vr, p.hbuf + (size_t)(pw * NL + 0) * HDIM, lane);
      else
        load_vec_coh(vr, p.hbuf + (size_t)(pr * NL + 1) * HDIM, lane);
      float acc[8];
#pragma unroll
      for (int r = 0; r < 8; ++r) acc[r] = 0.f;
#pragma unroll
      for (int j = 0; j < 4; ++j) {
        VM_DRAIN();
        consume_q(qA, vr, j, acc);
        if (j < 3) issue_q(rows1, j + 1, lane, qA);
      }
      if (s != NSTEPS - 1)
        issue_q(rows0, 0, lane, qA);     // prefetch next step L0 quarter 0
#pragma unroll
      for (int r = 0; r < 8; ++r) {
        float v = wave_sum(acc[r]);
        if (lane == 0) part_l[w][r] = v;
      }
      BSYNC();
      if (tid < 32) {
        const int c = tid >> 2, g = tid & 3;
        const int w0 = (c >> 1) * 2, idx = (c & 1) * 4 + g;
        gates[c][g] = part_l[w0][idx] + part_l[w0 + 1][idx] + b1v;
      }
      if (tid < 8) {
        float gi = 1.f / (1.f + expf(-gates[tid][0]));
        float gf = 1.f / (1.f + expf(-gates[tid][1]));
        float gg = tanhf(gates[tid][2]);
        float go = 1.f / (1.f + expf(-gates[tid][3]));
        c1 = gf * c1 + gi * gg;
        float h = go * tanhf(c1);
        st_coh_f32(&p.hbuf[(size_t)(pw * NL + 1) * HDIM + cell0 + tid], h);
        h1loc[tid] = h;
      }
      // h1loc: written lanes 0-7, read lanes 0-63 (same wave, in-order DS)
      if (w == 0) {
        float a2 = 0.f;
#pragma unroll
        for (int c = 0; c < 8; ++c) a2 = fmaf(hw[c], h1loc[c], a2);
        st_coh_f32(&p.part[(size_t)lane * NBLK + bid], a2);
      }
      gbar(++bt, tid, bid);  // all 256 partials visible grid-wide
    }

    // ================= deterministic logits reduce =================
    {
      const int a = tid >> 3, j = tid & 7;  // 8 threads per action
      const float* pb = p.part + (size_t)a * NBLK + j * 32;
      f4 t[8];
#pragma unroll
      for (int q = 0; q < 8; ++q) {
        const float* pq = pb + q * 4;
        asm volatile("global_load_dwordx4 %0, %1, off sc0 sc1"
                     : "=v"(t[q]) : "v"(pq) : "memory");
      }
      VM_DRAIN();   // also lands the L0-next weight prefetch (harmless wait)
      float sum = 0.f;
#pragma unroll
      for (int q = 0; q < 8; ++q) sum += t[q].x + t[q].y + t[q].z + t[q].w;
      sum += __shfl_xor(sum, 1);
      sum += __shfl_xor(sum, 2);
      sum += __shfl_xor(sum, 4);
      if (j == 0) lds_logits[a] = sum;
    }
    BSYNC();

    // ====== sampling (partitionable threefry, jax>=0.4.30 default) ======
    {
      float logit = lds_logits[lane] + p.head_b[s * NACT + lane];

      u32 kA, kB;
      tf2x32(0u, 42u, 0u, (u32)s, kA, kB);
      u32 y0, y1;
      tf2x32(kA, kB, 0u, (u32)lane, y0, y1);
      u32 bits = y0 ^ y1;

      float uf = __uint_as_float(0x3f800000u | (bits >> 9)) - 1.0f;
      const float tiny = 1.17549435e-38f;
      float u = fmaxf(tiny, uf + tiny);
      float gum = -logf(-logf(u));

      float score = logit + gum;
      int bi = lane;
      float bs = score;
#pragma unroll
      for (int off = 32; off > 0; off >>= 1) {
        float os = __shfl_xor(bs, off);
        int oi = __shfl_xor(bi, off);
        if (os > bs || (os == bs && oi < bi)) { bs = os; bi = oi; }
      }
      float mx = logit;
#pragma unroll
      for (int off = 32; off > 0; off >>= 1) mx = fmaxf(mx, __shfl_xor(mx, off));
      float se = wave_sum(expf(logit - mx));
      float la = __shfl(logit, bi);
      logp_sum += la - mx - logf(se);
      act = bi;
      if (bid == 0 && tid == 0) p.out[s] = (float)bi;
    }
    // lds_logits reuse protected by next step's barriers
  }
  if (bid == 0 && tid == 0) p.out[NSTEPS] = logp_sum;
}

// -------- init: f32->bf16 weights, head transpose, combined bias, zeroing ----
__global__ void init_kernel(const float* __restrict__ wih,
                            const float* __restrict__ whh,
                            const float* __restrict__ bih,
                            const float* __restrict__ bhh,
                            const float* __restrict__ head_w,
                            u16* __restrict__ wih_bf, u16* __restrict__ whh_bf,
                            float* __restrict__ head_wT,
                            float* __restrict__ bias, float* __restrict__ hbuf) {
  const size_t idx = (size_t)blockIdx.x * blockDim.x + threadIdx.x;
  const size_t stride = (size_t)gridDim.x * blockDim.x;
  const size_t n4 = (size_t)NL * 4 * HDIM * HDIM / 4;  // float4 count
  for (size_t k = idx; k < n4; k += stride) {
    float4 a = reinterpret_cast<const float4*>(wih)[k];
    float4 b = reinterpret_cast<const float4*>(whh)[k];
    ushort4 ua, ub;
    ua.x = to_bf16(a.x); ua.y = to_bf16(a.y);
    ua.z = to_bf16(a.z); ua.w = to_bf16(a.w);
    ub.x = to_bf16(b.x); ub.y = to_bf16(b.y);
    ub.z = to_bf16(b.z); ub.w = to_bf16(b.w);
    reinterpret_cast<ushort4*>(wih_bf)[k] = ua;
    reinterpret_cast<ushort4*>(whh_bf)[k] = ub;
  }
  // head_wT[s][h][a] = head_w[s][a][h]
  for (size_t k = idx; k < (size_t)NSTEPS * HDIM * NACT; k += stride) {
    const int a = (int)(k & (NACT - 1));
    const int h = (int)((k >> 6) & (HDIM - 1));
    const int s = (int)(k >> 17);
    head_wT[k] = head_w[((size_t)s * NACT + a) * HDIM + h];
  }
  for (size_t k = idx; k < (size_t)NL * 4 * HDIM; k += stride)
    bias[k] = bih[k] + bhh[k];
  for (size_t k = idx; k < (size_t)2 * NL * HDIM; k += stride) hbuf[k] = 0.f;
  // barrier state reset each launch (kernel-boundary release makes it visible)
  for (size_t k = idx; k < NBLK; k += stride) g_flags[k] = 0u;
  for (size_t k = idx; k < 64; k += stride) g_gen[k] = 0u;
}

extern "C" void kernel_launch(void* const* d_in, const int* in_sizes, int n_in,
                              void* d_out, int out_size, void* d_ws,
                              size_t ws_size, hipStream_t stream) {
  (void)in_sizes; (void)n_in; (void)out_size; (void)ws_size;
  const float* start_token = (const float*)d_in[0];
  const float* action_emb  = (const float*)d_in[1];
  const float* w_ih        = (const float*)d_in[2];
  const float* w_hh        = (const float*)d_in[3];
  const float* b_ih        = (const float*)d_in[4];
  const float* b_hh        = (const float*)d_in[5];
  const float* head_w      = (const float*)d_in[6];
  const float* head_b      = (const float*)d_in[7];

  char* ws = (char*)d_ws;
  const size_t WN = (size_t)NL * 4 * HDIM * HDIM;      // 33,554,432 elems
  u16* wih_bf    = (u16*)ws;                           // WN*2 bytes
  u16* whh_bf    = (u16*)(ws + WN * 2);                // WN*2 bytes
  size_t off     = WN * 4;
  float* head_wT = (float*)(ws + off); off += (size_t)NSTEPS * HDIM * NACT * 4;
  float* bias    = (float*)(ws + off); off += (size_t)NL * 4 * HDIM * 4;
  float* hbuf    = (float*)(ws + off); off += (size_t)2 * NL * HDIM * 4;
  float* partb   = (float*)(ws + off); off += (size_t)NACT * NBLK * 4;
  // NOTE: identical workspace footprint to the proven kernels.

  init_kernel<<<dim3(2048), dim3(256), 0, stream>>>(
      w_ih, w_hh, b_ih, b_hh, head_w, wih_bf, whh_bf, head_wT, bias, hbuf);

  Params p;
  p.start_token = start_token;
  p.action_emb = action_emb;
  p.head_wT = head_wT;
  p.head_b = head_b;
  p.wih = wih_bf;
  p.whh = whh_bf;
  p.bias = bias;
  p.hbuf = hbuf;
  p.part = partb;
  p.out = (float*)d_out;

  lstm_main<<<dim3(NBLK), dim3(TPB), 0, stream>>>(p);
}